// Round 12
// baseline (264.891 us; speedup 1.0000x reference)
//
#include <hip/hip_runtime.h>
#include <cstdint>
#include <cstddef>

#define S_LEN   2048
#define N_HEADS 8
#define N_BATCH 2
#define TOPK    409      // int(2048 * (1.0 - 0.8)) in python double arithmetic
#define HALF_WIN 32
#define KEY_P0  0x80000000u   // mono(+0.0f)
#define KEY_N0  0x7FFFFFFFu   // mono(-0.0f)  (total order: -0 < +0)

__device__ __forceinline__ unsigned mbcnt64(unsigned long long m) {
  return __builtin_amdgcn_mbcnt_hi((unsigned)(m >> 32),
         __builtin_amdgcn_mbcnt_lo((unsigned)m, 0u));
}

__device__ __forceinline__ unsigned mono1(float f) {
  unsigned u = __float_as_uint(f);
  return (u & 0x80000000u) ? ~u : (u | 0x80000000u);
}

// MSD radix select over the positive (key>+0) or negative (key<-0) subset.
// Wave-scope (no barriers). Keys accessed via getter G (regs or LDS).
template <class G>
__device__ __forceinline__ void radix_rangeT(G get, unsigned kk0, bool pos,
                                             unsigned* h, int l,
                                             unsigned& T_ret, unsigned& kk_ret,
                                             bool& cnt1) {
  unsigned prefix = 0, done = 0, kk = kk0;
  unsigned T = 0;
  bool resolved = false;
  cnt1 = false;
  #pragma unroll
  for (int pass = 0; pass < 4; ++pass) {
    const int shift = 24 - 8 * pass;
    *(uint4*)&h[l * 4] = make_uint4(0, 0, 0, 0);
    __threadfence_block();
    #pragma unroll
    for (int q = 0; q < 32; ++q) {
      unsigned kj = get(q);
      bool in = pos ? (kj > KEY_P0) : (kj < KEY_N0);
      if (in && (kj & done) == prefix)
        atomicAdd(&h[(kj >> shift) & 255u], 1u);
    }
    __threadfence_block();
    uint4 hv = *(const uint4*)&h[l * 4];
    unsigned s3 = hv.w;
    unsigned s2 = hv.z + s3;
    unsigned s1 = hv.y + s2;
    unsigned s0 = hv.x + s1;
    unsigned inc = s0;
    #pragma unroll
    for (int d = 1; d < 64; d <<= 1) {
      unsigned o = __shfl_down(inc, d);
      inc += (l + d < 64) ? o : 0u;
    }
    const unsigned tail = inc - s0;
    const unsigned ge[4] = {s0 + tail, s1 + tail, s2 + tail, s3 + tail};
    const unsigned gt[4] = {s1 + tail, s2 + tail, s3 + tail, tail};
    unsigned packed = 0;
    bool found = false;
    #pragma unroll
    for (int q = 0; q < 4; ++q) {
      if (gt[q] < kk && kk <= ge[q]) {
        packed = ((unsigned)(4 * l + q) << 24) | ((ge[q] - gt[q]) << 12) | (kk - gt[q]);
        found = true;
      }
    }
    unsigned long long bal = __ballot(found);
    int srcl = __ffsll((long long)bal) - 1;
    packed = __shfl(packed, srcl);
    const unsigned cnt = (packed >> 12) & 0xFFFu;
    kk = packed & 0xFFFu;
    prefix |= (packed >> 24) << shift;
    done |= 0xFFu << shift;
    if (cnt == 1u) {
      unsigned cand = 0;
      #pragma unroll
      for (int q = 0; q < 32; ++q) {
        unsigned kj = get(q);
        bool in = pos ? (kj > KEY_P0) : (kj < KEY_N0);
        if (in && (kj & done) == prefix) cand = kj;
      }
      #pragma unroll
      for (int d = 1; d < 64; d <<= 1) cand |= __shfl_xor(cand, d);
      T = cand;                              // kk == 1 here
      resolved = true;
      cnt1 = true;
      break;
    }
  }
  if (!resolved) T = prefix;
  T_ret = T;
  kk_ret = kk;
}

// Resolve threshold T + tie-take count kk for top-TOPK of 2048 keys (32/lane
// via getter). Order: positives > +0 > -0 > negatives; n0/n1 counted lazily.
template <class G>
__device__ __forceinline__ void resolve_TT(G get, unsigned* h, int l,
                                           unsigned& T, unsigned& kk, bool& cnt1) {
  unsigned np = 0;
  #pragma unroll
  for (int q = 0; q < 32; ++q)
    np += (unsigned)__popcll(__ballot(get(q) > KEY_P0));
  if (TOPK <= np) {
    radix_rangeT(get, TOPK, true, h, l, T, kk, cnt1);
  } else {
    unsigned n0 = 0, n1 = 0;
    #pragma unroll
    for (int q = 0; q < 32; ++q) {
      unsigned kj = get(q);
      n0 += (unsigned)__popcll(__ballot(kj == KEY_P0));
      n1 += (unsigned)__popcll(__ballot(kj == KEY_N0));
    }
    if (TOPK <= np + n0)           { T = KEY_P0; kk = TOPK - np;      cnt1 = (n0 == 1); }
    else if (TOPK <= np + n0 + n1) { T = KEY_N0; kk = TOPK - np - n0; cnt1 = (n1 == 1); }
    else radix_rangeT(get, TOPK - np - n0 - n1, false, h, l, T, kk, cnt1);
  }
}

// Per-lane selection bits (bit q=4s+e <-> column j=256s+4l+e). Stable
// lowest-index-first tie handling; ballot-free fast path when cnt1.
template <class G>
__device__ __forceinline__ unsigned select_bitsT(G get, unsigned T, unsigned kk,
                                                 bool cnt1, int l) {
  unsigned bits = 0;
  if (cnt1) {
    #pragma unroll
    for (int q = 0; q < 32; ++q)
      bits |= (get(q) >= T ? 1u : 0u) << q;
    return bits;
  }
  unsigned S_tot = 0;
  #pragma unroll
  for (int s = 0; s < 8; ++s) {
    unsigned long long beq[4];
    unsigned pe[4];
    #pragma unroll
    for (int e = 0; e < 4; ++e) {
      beq[e] = __ballot(get(4 * s + e) == T);
      pe[e] = (unsigned)__popcll(beq[e]);
    }
    const unsigned th = pe[0] + pe[1] + pe[2] + pe[3];
    if (S_tot + th <= kk) {
      #pragma unroll
      for (int e = 0; e < 4; ++e)
        bits |= (get(4 * s + e) >= T ? 1u : 0u) << (4 * s + e);
    } else if (S_tot >= kk) {
      #pragma unroll
      for (int e = 0; e < 4; ++e)
        bits |= (get(4 * s + e) > T ? 1u : 0u) << (4 * s + e);
    } else {                                 // boundary block (exactly one)
      unsigned mb[4], own[4];
      #pragma unroll
      for (int e = 0; e < 4; ++e) {
        mb[e]  = mbcnt64(beq[e]);
        own[e] = (unsigned)((beq[e] >> l) & 1ull);
      }
      const unsigned cross = S_tot + mb[0] + mb[1] + mb[2] + mb[3];
      unsigned run = 0;
      #pragma unroll
      for (int e = 0; e < 4; ++e) {
        unsigned kj = get(4 * s + e);
        bool sel = (kj > T) || (kj == T && (cross + run) < kk);
        run += own[e];
        bits |= (sel ? 1u : 0u) << (4 * s + e);
      }
    }
    S_tot += th;
  }
  return bits;
}

// Fused kernel: block = (b,i), 8 waves = 8 heads. Two-step staged head-sum
// (32KB stage reused for heads 0-3 then 4-7; association identical to the
// sequential reference mean). Own score row in registers (launch_bounds
// (512,4) -> VGPR cap 128, NO spill; R10/R11's (512,6) spilled sb[32] to
// scratch = +430MB HBM traffic). Gmask keys stored TRANSPOSED in gsum
// (key of column 256w+4l+e at gsum[(4w+e)*64+l]) so wave 0's select getter
// reads stride-1 across lanes = conflict-free.
__global__ __launch_bounds__(512, 4) void k_fused(const float* __restrict__ scores,
                                                  const float* __restrict__ randu,
                                                  float* __restrict__ out) {
  __shared__ __align__(16) float stage[4][S_LEN];      // 32 KB
  __shared__ __align__(16) unsigned gsum[S_LEN];       // 8 KB: partial sums,
                                                       // then TRANSPOSED keys
  __shared__ __align__(16) unsigned hist[N_HEADS][256];// 8 KB
  __shared__ unsigned gq[64];                          // shared select words
  const int l = threadIdx.x & 63;          // lane
  const int w = threadIdx.x >> 6;          // wave = head
  const int bi = blockIdx.x;               // b * S + i
  const int b = bi >> 11;
  const int i = bi & 2047;
  const size_t row = (((size_t)(b * N_HEADS + w)) * S_LEN + i) * S_LEN;
  const float thr = (float)(1.0 - 0.8);    // 0x3E4CCCCD, JAX f32 demotion

  // ---- P1: load own row to regs (raw bits); stage heads 0-3; rand bits ----
  unsigned sb[32];                          // raw score bits, later keys
  unsigned rndbits = 0;
  #pragma unroll
  for (int s = 0; s < 8; ++s) {
    const int j0 = 256 * s + 4 * l;
    float4 sc = *(const float4*)(scores + row + j0);
    float4 ru = *(const float4*)(randu + row + j0);
    sb[4 * s + 0] = __float_as_uint(sc.x);
    sb[4 * s + 1] = __float_as_uint(sc.y);
    sb[4 * s + 2] = __float_as_uint(sc.z);
    sb[4 * s + 3] = __float_as_uint(sc.w);
    rndbits |= (ru.x < thr ? 1u : 0u) << (4 * s + 0);
    rndbits |= (ru.y < thr ? 1u : 0u) << (4 * s + 1);
    rndbits |= (ru.z < thr ? 1u : 0u) << (4 * s + 2);
    rndbits |= (ru.w < thr ? 1u : 0u) << (4 * s + 3);
    if (w < 4) *(float4*)&stage[w][j0] = sc;
  }
  __syncthreads();

  // ---- P2a: partial sum heads 0-3 over this wave's 256-column slice ----
  {
    const int c0 = 256 * w + 4 * l;
    float4 a = *(const float4*)&stage[0][c0];
    #pragma unroll
    for (int hh = 1; hh < 4; ++hh) {
      float4 x = *(const float4*)&stage[hh][c0];
      a.x += x.x; a.y += x.y; a.z += x.z; a.w += x.w;
    }
    *(float4*)&gsum[c0] = a;
  }
  __syncthreads();

  // ---- P2b: waves 4-7 overwrite stage with their rows ----
  if (w >= 4) {
    #pragma unroll
    for (int s = 0; s < 8; ++s)
      *(uint4*)&stage[w - 4][256 * s + 4 * l] = *(const uint4*)&sb[4 * s];
  }
  __syncthreads();

  // ---- P2c: finish sum (heads 4-7, in order), monotonize, write keys
  //      TRANSPOSED into gsum (own wave's region only; in-order LDS) ----
  {
    const int c0 = 256 * w + 4 * l;
    float4 a = *(const float4*)&gsum[c0];
    #pragma unroll
    for (int hh = 0; hh < 4; ++hh) {
      float4 x = *(const float4*)&stage[hh][c0];
      a.x += x.x; a.y += x.y; a.z += x.z; a.w += x.w;
    }
    const float av[4] = {a.x, a.y, a.z, a.w};
    #pragma unroll
    for (int e = 0; e < 4; ++e)
      gsum[(4 * w + e) * 64 + l] = mono1(av[e]);   // column 256w+4l+e
  }
  __syncthreads();

  // ---- P3a: wave 0 computes the gmask select once, publishes gq[l] ----
  if (w == 0) {
    auto getG = [&](int q) -> unsigned {
      return gsum[q * 64 + l];               // stride-1: conflict-free
    };
    unsigned Tg, kkg; bool c1g;
    resolve_TT(getG, hist[0], l, Tg, kkg, c1g);
    unsigned gbits = select_bitsT(getG, Tg, kkg, c1g, l);
    const int lo = i - HALF_WIN;             // window [i-32, i+32)
    #pragma unroll
    for (int q = 0; q < 32; ++q) {
      const int j = 256 * (q >> 2) + 4 * l + (q & 3);
      gbits |= ((unsigned)(j - lo) < 64u ? 1u : 0u) << q;
    }
    gq[l] = gbits;
  }
  __syncthreads();

  // ---- P3b: build keys in place, per-head top-k, write ----
  const unsigned combined = gq[l] | rndbits;
  #pragma unroll
  for (int q = 0; q < 32; ++q) {
    const unsigned u = sb[q];
    const unsigned m = (unsigned)((int)u >> 31) | 0x80000000u;
    const bool comb = ((combined >> q) & 1u) != 0u;
    sb[q] = (comb ? u : (u & 0x80000000u)) ^ m;
  }
  auto getK = [&](int q) -> unsigned { return sb[q]; };
  unsigned T, kk; bool c1;
  resolve_TT(getK, hist[w], l, T, kk, c1);
  unsigned bits = select_bitsT(getK, T, kk, c1, l);
  #pragma unroll
  for (int s = 0; s < 8; ++s) {
    float v[4] __attribute__((aligned(16)));
    #pragma unroll
    for (int e = 0; e < 4; ++e)
      v[e] = ((bits >> (4 * s + e)) & 1u) ? 1.0f : 0.0f;
    *(float4*)(out + row + 256 * s + 4 * l) = *(const float4*)v;
  }
}

extern "C" void kernel_launch(void* const* d_in, const int* in_sizes, int n_in,
                              void* d_out, int out_size, void* d_ws, size_t ws_size,
                              hipStream_t stream) {
  const float* scores = (const float*)d_in[0];
  const float* randu  = (const float*)d_in[1];
  float* out = (float*)d_out;
  (void)d_ws; (void)ws_size;
  k_fused<<<N_BATCH * S_LEN, 512, 0, stream>>>(scores, randu, out);
}

// Round 14
// 203.820 us; speedup vs baseline: 1.2996x; 1.2996x over previous
//
#include <hip/hip_runtime.h>
#include <cstdint>
#include <cstddef>

#define S_LEN   2048
#define N_HEADS 8
#define N_BATCH 2
#define TOPK    409      // int(2048 * (1.0 - 0.8)) in python double arithmetic
#define HALF_WIN 32
#define KEY_P0  0x80000000u   // mono(+0.0f)
#define KEY_N0  0x7FFFFFFFu   // mono(-0.0f)  (total order: -0 < +0)
#define HIST_STRIDE 260       // words; staggers hist rows by 4 banks per wave

__device__ __forceinline__ unsigned mbcnt64(unsigned long long m) {
  return __builtin_amdgcn_mbcnt_hi((unsigned)(m >> 32),
         __builtin_amdgcn_mbcnt_lo((unsigned)m, 0u));
}

__device__ __forceinline__ unsigned mono1(float f) {
  unsigned u = __float_as_uint(f);
  return (u & 0x80000000u) ? ~u : (u | 0x80000000u);
}

// MSD radix select over the positive (key>+0) or negative (key<-0) subset.
// Wave-scope (no barriers). Keys in a register array.
__device__ __forceinline__ void radix_range(const unsigned (&keys)[32], unsigned kk0,
                                            bool pos, unsigned* h, int l,
                                            unsigned& T_ret, unsigned& kk_ret,
                                            bool& cnt1) {
  unsigned prefix = 0, done = 0, kk = kk0;
  unsigned T = 0;
  bool resolved = false;
  cnt1 = false;
  #pragma unroll
  for (int pass = 0; pass < 4; ++pass) {
    const int shift = 24 - 8 * pass;
    *(uint4*)&h[l * 4] = make_uint4(0, 0, 0, 0);
    __threadfence_block();
    #pragma unroll
    for (int q = 0; q < 32; ++q) {
      unsigned kj = keys[q];
      bool in = pos ? (kj > KEY_P0) : (kj < KEY_N0);
      if (in && (kj & done) == prefix)
        atomicAdd(&h[(kj >> shift) & 255u], 1u);
    }
    __threadfence_block();
    uint4 hv = *(const uint4*)&h[l * 4];
    unsigned s3 = hv.w;
    unsigned s2 = hv.z + s3;
    unsigned s1 = hv.y + s2;
    unsigned s0 = hv.x + s1;
    unsigned inc = s0;
    #pragma unroll
    for (int d = 1; d < 64; d <<= 1) {
      unsigned o = __shfl_down(inc, d);
      inc += (l + d < 64) ? o : 0u;
    }
    const unsigned tail = inc - s0;
    const unsigned ge[4] = {s0 + tail, s1 + tail, s2 + tail, s3 + tail};
    const unsigned gt[4] = {s1 + tail, s2 + tail, s3 + tail, tail};
    unsigned packed = 0;
    bool found = false;
    #pragma unroll
    for (int q = 0; q < 4; ++q) {
      if (gt[q] < kk && kk <= ge[q]) {
        packed = ((unsigned)(4 * l + q) << 24) | ((ge[q] - gt[q]) << 12) | (kk - gt[q]);
        found = true;
      }
    }
    unsigned long long bal = __ballot(found);
    int srcl = __ffsll((long long)bal) - 1;
    packed = __shfl(packed, srcl);
    const unsigned cnt = (packed >> 12) & 0xFFFu;
    kk = packed & 0xFFFu;
    prefix |= (packed >> 24) << shift;
    done |= 0xFFu << shift;
    if (cnt == 1u) {
      unsigned cand = 0;
      #pragma unroll
      for (int q = 0; q < 32; ++q) {
        unsigned kj = keys[q];
        bool in = pos ? (kj > KEY_P0) : (kj < KEY_N0);
        if (in && (kj & done) == prefix) cand = kj;
      }
      #pragma unroll
      for (int d = 1; d < 64; d <<= 1) cand |= __shfl_xor(cand, d);
      T = cand;                              // kk == 1 here
      resolved = true;
      cnt1 = true;
      break;
    }
  }
  if (!resolved) T = prefix;
  T_ret = T;
  kk_ret = kk;
}

// Resolve threshold T + tie-take count kk for top-TOPK of 2048 keys (32/lane).
// Order: positives > +0 > -0 > negatives; n0/n1 counted lazily.
__device__ __forceinline__ void resolve_T(const unsigned (&keys)[32], unsigned* h,
                                          int l, unsigned& T, unsigned& kk,
                                          bool& cnt1) {
  unsigned np = 0;
  #pragma unroll
  for (int q = 0; q < 32; ++q)
    np += (unsigned)__popcll(__ballot(keys[q] > KEY_P0));
  if (TOPK <= np) {
    radix_range(keys, TOPK, true, h, l, T, kk, cnt1);
  } else {
    unsigned n0 = 0, n1 = 0;
    #pragma unroll
    for (int q = 0; q < 32; ++q) {
      unsigned kj = keys[q];
      n0 += (unsigned)__popcll(__ballot(kj == KEY_P0));
      n1 += (unsigned)__popcll(__ballot(kj == KEY_N0));
    }
    if (TOPK <= np + n0)           { T = KEY_P0; kk = TOPK - np;      cnt1 = (n0 == 1); }
    else if (TOPK <= np + n0 + n1) { T = KEY_N0; kk = TOPK - np - n0; cnt1 = (n1 == 1); }
    else radix_range(keys, TOPK - np - n0 - n1, false, h, l, T, kk, cnt1);
  }
}

// Per-lane selection bits (bit q=4s+e <-> column j=256s+4l+e). Stable
// lowest-index-first tie handling; ballot-free fast path when cnt1.
__device__ __forceinline__ unsigned select_bits(const unsigned (&keys)[32],
                                                unsigned T, unsigned kk,
                                                bool cnt1, int l) {
  unsigned bits = 0;
  if (cnt1) {
    #pragma unroll
    for (int q = 0; q < 32; ++q)
      bits |= (keys[q] >= T ? 1u : 0u) << q;
    return bits;
  }
  unsigned S_tot = 0;
  #pragma unroll
  for (int s = 0; s < 8; ++s) {
    unsigned long long beq[4];
    unsigned pe[4];
    #pragma unroll
    for (int e = 0; e < 4; ++e) {
      beq[e] = __ballot(keys[4 * s + e] == T);
      pe[e] = (unsigned)__popcll(beq[e]);
    }
    const unsigned th = pe[0] + pe[1] + pe[2] + pe[3];
    if (S_tot + th <= kk) {
      #pragma unroll
      for (int e = 0; e < 4; ++e)
        bits |= (keys[4 * s + e] >= T ? 1u : 0u) << (4 * s + e);
    } else if (S_tot >= kk) {
      #pragma unroll
      for (int e = 0; e < 4; ++e)
        bits |= (keys[4 * s + e] > T ? 1u : 0u) << (4 * s + e);
    } else {                                 // boundary block (exactly one)
      unsigned mb[4], own[4];
      #pragma unroll
      for (int e = 0; e < 4; ++e) {
        mb[e]  = mbcnt64(beq[e]);
        own[e] = (unsigned)((beq[e] >> l) & 1ull);
      }
      const unsigned cross = S_tot + mb[0] + mb[1] + mb[2] + mb[3];
      unsigned run = 0;
      #pragma unroll
      for (int e = 0; e < 4; ++e) {
        unsigned kj = keys[4 * s + e];
        bool sel = (kj > T) || (kj == T && (cross + run) < kk);
        run += own[e];
        bits |= (sel ? 1u : 0u) << (4 * s + e);
      }
    }
    S_tot += th;
  }
  return bits;
}

// Fused kernel: block = (b,i), 8 waves = 8 heads. R9 structure (single 64KB
// staging, register selects) with two fixes:
//  - head-sum parallelized: each wave sums its 256-col slice (sequential head
//    order per column = bit-exact) and writes mono keys TRANSPOSED into gsum
//    (gsum[(4w+e)*64+l] = key of column 256w+4l+e); wave 0 reloads all 2048
//    keys into registers via 32 conflict-free stride-1 reads.
//  - hist rows live in the dead stage[] memory at stride 260 words -> wave w's
//    row starts at bank 4w: no cross-wave hot-bin conflicts.
__global__ __launch_bounds__(512, 4) void k_fused(const float* __restrict__ scores,
                                                  const float* __restrict__ randu,
                                                  float* __restrict__ out) {
  __shared__ __align__(16) float stage[N_HEADS][S_LEN];  // 64 KB; hist after P2
  __shared__ __align__(16) unsigned gsum[S_LEN];         // 8 KB transposed keys
  __shared__ unsigned gq[64];                            // shared select words
  const int l = threadIdx.x & 63;          // lane
  const int w = threadIdx.x >> 6;          // wave = head
  const int bi = blockIdx.x;               // b * S + i
  const int b = bi >> 11;
  const int i = bi & 2047;
  const size_t row = (((size_t)(b * N_HEADS + w)) * S_LEN + i) * S_LEN;
  const float thr = (float)(1.0 - 0.8);    // 0x3E4CCCCD, JAX f32 demotion
  unsigned* const hist_base = (unsigned*)stage;          // alias: dead after P2
  unsigned* const h = hist_base + (size_t)w * HIST_STRIDE;

  // ---- P1: own row to regs (raw bits); stage own row; rand bits ----
  unsigned sb[32];                          // raw score bits, later keys
  unsigned rndbits = 0;
  #pragma unroll
  for (int s = 0; s < 8; ++s) {
    const int j0 = 256 * s + 4 * l;
    float4 sc = *(const float4*)(scores + row + j0);
    float4 ru = *(const float4*)(randu + row + j0);
    sb[4 * s + 0] = __float_as_uint(sc.x);
    sb[4 * s + 1] = __float_as_uint(sc.y);
    sb[4 * s + 2] = __float_as_uint(sc.z);
    sb[4 * s + 3] = __float_as_uint(sc.w);
    rndbits |= (ru.x < thr ? 1u : 0u) << (4 * s + 0);
    rndbits |= (ru.y < thr ? 1u : 0u) << (4 * s + 1);
    rndbits |= (ru.z < thr ? 1u : 0u) << (4 * s + 2);
    rndbits |= (ru.w < thr ? 1u : 0u) << (4 * s + 3);
    *(float4*)&stage[w][j0] = sc;
  }
  __syncthreads();

  // ---- P2: per-slice head-sum (sequential h order), transposed keys ----
  {
    const int c0 = 256 * w + 4 * l;
    float4 a = *(const float4*)&stage[0][c0];
    #pragma unroll
    for (int hh = 1; hh < N_HEADS; ++hh) {
      float4 x = *(const float4*)&stage[hh][c0];
      a.x += x.x; a.y += x.y; a.z += x.z; a.w += x.w;
    }
    const float av[4] = {a.x, a.y, a.z, a.w};
    #pragma unroll
    for (int e = 0; e < 4; ++e)
      gsum[(4 * w + e) * 64 + l] = mono1(av[e]);   // column 256w+4l+e
  }
  __syncthreads();

  // ---- P3a: wave 0 reloads keys to regs, selects, publishes gq[l] ----
  if (w == 0) {
    unsigned gk[32];
    #pragma unroll
    for (int q = 0; q < 32; ++q)
      gk[q] = gsum[q * 64 + l];              // stride-1: conflict-free
    unsigned Tg, kkg; bool c1g;
    resolve_T(gk, hist_base, l, Tg, kkg, c1g);
    unsigned gbits = select_bits(gk, Tg, kkg, c1g, l);
    const int lo = i - HALF_WIN;             // window [i-32, i+32)
    #pragma unroll
    for (int q = 0; q < 32; ++q) {
      const int j = 256 * (q >> 2) + 4 * l + (q & 3);
      gbits |= ((unsigned)(j - lo) < 64u ? 1u : 0u) << q;
    }
    gq[l] = gbits;
  }
  __syncthreads();

  // ---- P3b: build keys in place, per-head top-k, write ----
  const unsigned combined = gq[l] | rndbits;
  #pragma unroll
  for (int q = 0; q < 32; ++q) {
    const unsigned u = sb[q];
    const unsigned m = (unsigned)((int)u >> 31) | 0x80000000u;
    const bool comb = ((combined >> q) & 1u) != 0u;
    sb[q] = (comb ? u : (u & 0x80000000u)) ^ m;
  }
  unsigned T, kk; bool c1;
  resolve_T(sb, h, l, T, kk, c1);
  unsigned bits = select_bits(sb, T, kk, c1, l);
  #pragma unroll
  for (int s = 0; s < 8; ++s) {
    float v[4] __attribute__((aligned(16)));
    #pragma unroll
    for (int e = 0; e < 4; ++e)
      v[e] = ((bits >> (4 * s + e)) & 1u) ? 1.0f : 0.0f;
    *(float4*)(out + row + 256 * s + 4 * l) = *(const float4*)v;
  }
}

extern "C" void kernel_launch(void* const* d_in, const int* in_sizes, int n_in,
                              void* d_out, int out_size, void* d_ws, size_t ws_size,
                              hipStream_t stream) {
  const float* scores = (const float*)d_in[0];
  const float* randu  = (const float*)d_in[1];
  float* out = (float*)d_out;
  (void)d_ws; (void)ws_size;
  k_fused<<<N_BATCH * S_LEN, 512, 0, stream>>>(scores, randu, out);
}